// Round 6
// baseline (108.525 us; speedup 1.0000x reference)
//
#include <hip/hip_runtime.h>

typedef _Float16 half8 __attribute__((ext_vector_type(8)));
typedef float f32x4 __attribute__((ext_vector_type(4)));

namespace {

constexpr int HEADS = 8;
constexpr int BATCH = 512;
constexpr int DH    = 1024;          // per-head dim
constexpr int CHW   = HEADS * DH;    // 8192

constexpr int BM = 128, BN = 128;

// dispatch-index d runs on XCD d%8; give each XCD a contiguous logical chunk
__device__ __forceinline__ int xcd_swz(int bid, int nwg) {
  const int q = nwg >> 3;  // all our grids are %8 == 0
  return (bid & 7) * q + (bid >> 3);
}

// async global->LDS, 16 bytes per lane (literal size arg required)
typedef __attribute__((address_space(3))) unsigned int lds_u32;
typedef const __attribute__((address_space(1))) unsigned int glb_u32;
__device__ __forceinline__ void gl_lds16(const void* g, void* l) {
  __builtin_amdgcn_global_load_lds((glb_u32*)g, (lds_u32*)l, 16, 0, 0);
}

// static-only f32x8 -> f16x8 conversion
__device__ __forceinline__ half8 cvt8(float4 a, float4 b) {
  half8 r;
  r[0] = (_Float16)a.x; r[1] = (_Float16)a.y; r[2] = (_Float16)a.z; r[3] = (_Float16)a.w;
  r[4] = (_Float16)b.x; r[5] = (_Float16)b.y; r[6] = (_Float16)b.z; r[7] = (_Float16)b.w;
  return r;
}

// ---------------------------------------------------------------------------
// Fused Q/K/V projection, f32 inputs. z selects (X, W, bias, dst).
// LDS holds f32 tiles [128 rows x 32 floats = 128B/row], staged by
// global_load_lds with XOR-swizzled SOURCE (16B block cb ^= row&7); ds_read
// uses the same XOR. cvt f32->f16 on the consume side.
// ---------------------------------------------------------------------------
__global__ __launch_bounds__(256) void proj_kernel(
    const float* __restrict__ Xq, const float* __restrict__ Xk, const float* __restrict__ Xv,
    const float* __restrict__ W1, const float* __restrict__ b1,
    const float* __restrict__ W2, const float* __restrict__ b2,
    const float* __restrict__ W3, const float* __restrict__ b3,
    _Float16* __restrict__ Qp, _Float16* __restrict__ Kp, _Float16* __restrict__ VpT) {
  __shared__ __align__(16) float As[BM * 32];   // 16 KB
  __shared__ __align__(16) float Bs[BN * 32];   // 16 KB
  const int tid = threadIdx.x;
  const int l  = xcd_swz(blockIdx.x, 768);
  const int z  = l >> 8, rem = l & 255;
  const int h  = rem >> 5, bx = rem & 31;
  const int tm = bx & 3, tn = bx >> 2;
  const float* X    = (z == 0) ? Xq : (z == 1) ? Xk : Xv;
  const float* W    = (z == 0) ? W1 : (z == 1) ? W2 : W3;
  const float* bias = (z == 0) ? b1 : (z == 1) ? b2 : b3;
  _Float16*    P    = (z == 0) ? Qp : (z == 1) ? Kp : VpT;

  const int lane = tid & 63, w = tid >> 6;
  const int wr = (w >> 1) * 64, wc = (w & 1) * 64;
  const int lr = lane & 15, lk = lane >> 4;

  const char* Ab = (const char*)(X + (size_t)tm * BM * CHW + (size_t)h * DH);
  const char* Bb = (const char*)(W + (size_t)h * DH * DH + (size_t)tn * BN * DH);

  // staging map: linear LDS byte off = r*4096 + tid*16 -> (row = off>>7,
  // cb = (off>>4)&7); source reads block (cb ^ (row&7)) of that row.
  const char* srcA0; const char* srcA1; const char* srcA2; const char* srcA3;
  const char* srcB0; const char* srcB1; const char* srcB2; const char* srcB3;
  int off0, off1, off2, off3;
  {
    int off, row, scb;
    off = 0 * 4096 + tid * 16; row = off >> 7; scb = ((off >> 4) & 7) ^ (row & 7);
    off0 = off; srcA0 = Ab + (size_t)row * (CHW * 4) + scb * 16; srcB0 = Bb + (size_t)row * (DH * 4) + scb * 16;
    off = 1 * 4096 + tid * 16; row = off >> 7; scb = ((off >> 4) & 7) ^ (row & 7);
    off1 = off; srcA1 = Ab + (size_t)row * (CHW * 4) + scb * 16; srcB1 = Bb + (size_t)row * (DH * 4) + scb * 16;
    off = 2 * 4096 + tid * 16; row = off >> 7; scb = ((off >> 4) & 7) ^ (row & 7);
    off2 = off; srcA2 = Ab + (size_t)row * (CHW * 4) + scb * 16; srcB2 = Bb + (size_t)row * (DH * 4) + scb * 16;
    off = 3 * 4096 + tid * 16; row = off >> 7; scb = ((off >> 4) & 7) ^ (row & 7);
    off3 = off; srcA3 = Ab + (size_t)row * (CHW * 4) + scb * 16; srcB3 = Bb + (size_t)row * (DH * 4) + scb * 16;
  }

  constexpr int NT = DH / 32;  // 32 K-steps
  f32x4 acc[4][4] = {};
#pragma unroll 1
  for (int t = 0; t < NT; ++t) {
    __syncthreads();  // previous tile fully consumed
    gl_lds16(srcA0, (char*)As + off0); gl_lds16(srcB0, (char*)Bs + off0);
    gl_lds16(srcA1, (char*)As + off1); gl_lds16(srcB1, (char*)Bs + off1);
    gl_lds16(srcA2, (char*)As + off2); gl_lds16(srcB2, (char*)Bs + off2);
    gl_lds16(srcA3, (char*)As + off3); gl_lds16(srcB3, (char*)Bs + off3);
    srcA0 += 128; srcA1 += 128; srcA2 += 128; srcA3 += 128;
    srcB0 += 128; srcB1 += 128; srcB2 += 128; srcB3 += 128;
    __syncthreads();  // vmcnt(0) drained -> tile ready
    half8 av[4], bv[4];
#pragma unroll
    for (int i = 0; i < 4; ++i) {
      const int row = wr + i * 16 + lr;
      const float4 p0 = *(const float4*)&As[row * 32 + (((lk * 2)    ) ^ (row & 7)) * 4];
      const float4 p1 = *(const float4*)&As[row * 32 + (((lk * 2 + 1)) ^ (row & 7)) * 4];
      av[i] = cvt8(p0, p1);
    }
#pragma unroll
    for (int j = 0; j < 4; ++j) {
      const int row = wc + j * 16 + lr;
      const float4 p0 = *(const float4*)&Bs[row * 32 + (((lk * 2)    ) ^ (row & 7)) * 4];
      const float4 p1 = *(const float4*)&Bs[row * 32 + (((lk * 2 + 1)) ^ (row & 7)) * 4];
      bv[j] = cvt8(p0, p1);
    }
#pragma unroll
    for (int i = 0; i < 4; ++i)
#pragma unroll
      for (int j = 0; j < 4; ++j)
        acc[i][j] = __builtin_amdgcn_mfma_f32_16x16x32_f16(av[i], bv[j], acc[i][j], 0, 0, 0);
  }

#pragma unroll
  for (int i = 0; i < 4; ++i)
#pragma unroll
    for (int j = 0; j < 4; ++j) {
      const int e = tn * BN + wc + j * 16 + lr;
      const float bb = bias[h * DH + e];
#pragma unroll
      for (int q = 0; q < 4; ++q) {
        const int n = tm * BM + wr + i * 16 + lk * 4 + q;
        const float val = acc[i][j][q] + bb;
        if (z != 2) P[((size_t)h * BATCH + n) * DH + e] = (_Float16)val;
        else        P[((size_t)h * DH + e) * BATCH + n] = (_Float16)val;
      }
    }
}

// ---------------------------------------------------------------------------
// f16 NT-GEMM core, m97 structure: BK=64 (128B rows), global_load_lds with
// swizzled source, 2 barriers/K-step, 32KB single-buffer LDS.
// ---------------------------------------------------------------------------
template <int NT>
__device__ __forceinline__ void gemm16_core(
    const char* ga, size_t lda, const char* gb, size_t ldb,
    _Float16* As, _Float16* Bs,
    int tid, int wr, int wc, int lr, int lk, f32x4 (&acc)[4][4]) {
  const char* srcA0; const char* srcA1; const char* srcA2; const char* srcA3;
  const char* srcB0; const char* srcB1; const char* srcB2; const char* srcB3;
  int off0, off1, off2, off3;
  {
    int off, row, scb;
    off = 0 * 4096 + tid * 16; row = off >> 7; scb = ((off >> 4) & 7) ^ (row & 7);
    off0 = off; srcA0 = ga + (size_t)row * lda + scb * 16; srcB0 = gb + (size_t)row * ldb + scb * 16;
    off = 1 * 4096 + tid * 16; row = off >> 7; scb = ((off >> 4) & 7) ^ (row & 7);
    off1 = off; srcA1 = ga + (size_t)row * lda + scb * 16; srcB1 = gb + (size_t)row * ldb + scb * 16;
    off = 2 * 4096 + tid * 16; row = off >> 7; scb = ((off >> 4) & 7) ^ (row & 7);
    off2 = off; srcA2 = ga + (size_t)row * lda + scb * 16; srcB2 = gb + (size_t)row * ldb + scb * 16;
    off = 3 * 4096 + tid * 16; row = off >> 7; scb = ((off >> 4) & 7) ^ (row & 7);
    off3 = off; srcA3 = ga + (size_t)row * lda + scb * 16; srcB3 = gb + (size_t)row * ldb + scb * 16;
  }

#pragma unroll 1
  for (int t = 0; t < NT; ++t) {
    __syncthreads();
    gl_lds16(srcA0, (char*)As + off0); gl_lds16(srcB0, (char*)Bs + off0);
    gl_lds16(srcA1, (char*)As + off1); gl_lds16(srcB1, (char*)Bs + off1);
    gl_lds16(srcA2, (char*)As + off2); gl_lds16(srcB2, (char*)Bs + off2);
    gl_lds16(srcA3, (char*)As + off3); gl_lds16(srcB3, (char*)Bs + off3);
    srcA0 += 128; srcA1 += 128; srcA2 += 128; srcA3 += 128;
    srcB0 += 128; srcB1 += 128; srcB2 += 128; srcB3 += 128;
    __syncthreads();
    half8 a0[4], a1[4], b0[4], b1[4];
#pragma unroll
    for (int i = 0; i < 4; ++i) {
      const int row = wr + i * 16 + lr;
      a0[i] = *(const half8*)&As[row * 64 + ((lk    ) ^ (row & 7)) * 8];
      a1[i] = *(const half8*)&As[row * 64 + ((4 + lk) ^ (row & 7)) * 8];
    }
#pragma unroll
    for (int j = 0; j < 4; ++j) {
      const int row = wc + j * 16 + lr;
      b0[j] = *(const half8*)&Bs[row * 64 + ((lk    ) ^ (row & 7)) * 8];
      b1[j] = *(const half8*)&Bs[row * 64 + ((4 + lk) ^ (row & 7)) * 8];
    }
#pragma unroll
    for (int i = 0; i < 4; ++i)
#pragma unroll
      for (int j = 0; j < 4; ++j) {
        acc[i][j] = __builtin_amdgcn_mfma_f32_16x16x32_f16(a0[i], b0[j], acc[i][j], 0, 0, 0);
        acc[i][j] = __builtin_amdgcn_mfma_f32_16x16x32_f16(a1[i], b1[j], acc[i][j], 0, 0, 0);
      }
  }
}

// S[h,n,m] = 32 * sum_e Qp[h,n,e] * Kp[h,m,e]   (fp32 out)
__global__ __launch_bounds__(256) void score_kernel(
    const _Float16* __restrict__ Qp, const _Float16* __restrict__ Kp,
    float* __restrict__ S) {
  __shared__ __align__(16) _Float16 As[BM * 64];
  __shared__ __align__(16) _Float16 Bs[BN * 64];
  const int tid = threadIdx.x;
  const int l  = xcd_swz(blockIdx.x, 128);
  const int h  = l >> 4, bx = l & 15;
  const int tm = bx & 3, tn = bx >> 2;
  const int lane = tid & 63, w = tid >> 6;
  const int wr = (w >> 1) * 64, wc = (w & 1) * 64;
  const int lr = lane & 15, lk = lane >> 4;

  const char* ga = (const char*)(Qp + ((size_t)h * BATCH + tm * BM) * DH);
  const char* gb = (const char*)(Kp + ((size_t)h * BATCH + tn * BN) * DH);

  f32x4 acc[4][4] = {};
  gemm16_core<DH / 64>(ga, DH * 2, gb, DH * 2, As, Bs, tid, wr, wc, lr, lk, acc);

#pragma unroll
  for (int i = 0; i < 4; ++i)
#pragma unroll
    for (int j = 0; j < 4; ++j) {
      const int m = tn * BN + wc + j * 16 + lr;
#pragma unroll
      for (int q = 0; q < 4; ++q) {
        const int n = tm * BM + wr + i * 16 + lk * 4 + q;
        S[((size_t)h * BATCH + n) * BATCH + m] = 32.0f * acc[i][j][q];
      }
    }
}

// row-softmax over m (512), one wave per (h,n) row; fp32 in, fp16 out
__global__ __launch_bounds__(64) void softmax_kernel(
    const float* __restrict__ S, _Float16* __restrict__ A) {
  const size_t r = (size_t)blockIdx.x * BATCH;
  const int l = threadIdx.x;
  float v[8];
  float mx = -1e30f;
#pragma unroll
  for (int i = 0; i < 8; ++i) { v[i] = S[r + i * 64 + l]; mx = fmaxf(mx, v[i]); }
#pragma unroll
  for (int off = 32; off; off >>= 1) mx = fmaxf(mx, __shfl_xor(mx, off));
  float sum = 0.f;
#pragma unroll
  for (int i = 0; i < 8; ++i) { v[i] = __expf(v[i] - mx); sum += v[i]; }
#pragma unroll
  for (int off = 32; off; off >>= 1) sum += __shfl_xor(sum, off);
  const float inv = 1.f / sum;
#pragma unroll
  for (int i = 0; i < 8; ++i) A[r + i * 64 + l] = (_Float16)(v[i] * inv);
}

// Out[n,h,e] = sum_m At[h,n,m] * VpT[h,e,m]   (fp32 out)
__global__ __launch_bounds__(256) void pv_kernel(
    const _Float16* __restrict__ At, const _Float16* __restrict__ VpT,
    float* __restrict__ Out) {
  __shared__ __align__(16) _Float16 As[BM * 64];
  __shared__ __align__(16) _Float16 Bs[BN * 64];
  const int tid = threadIdx.x;
  const int l  = xcd_swz(blockIdx.x, 256);
  const int h  = l >> 5, bx = l & 31;
  const int tm = bx & 3, tn = bx >> 2;
  const int lane = tid & 63, w = tid >> 6;
  const int wr = (w >> 1) * 64, wc = (w & 1) * 64;
  const int lr = lane & 15, lk = lane >> 4;

  const char* ga = (const char*)(At  + ((size_t)h * BATCH + tm * BM) * BATCH);
  const char* gb = (const char*)(VpT + ((size_t)h * DH   + tn * BN) * BATCH);

  f32x4 acc[4][4] = {};
  gemm16_core<BATCH / 64>(ga, BATCH * 2, gb, BATCH * 2, As, Bs, tid, wr, wc, lr, lk, acc);

#pragma unroll
  for (int i = 0; i < 4; ++i)
#pragma unroll
    for (int j = 0; j < 4; ++j) {
      const int e = tn * BN + wc + j * 16 + lr;
#pragma unroll
      for (int q = 0; q < 4; ++q) {
        const int n = tm * BM + wr + i * 16 + lk * 4 + q;
        Out[((size_t)n * HEADS + h) * DH + e] = acc[i][j][q];
      }
    }
}

}  // namespace

extern "C" void kernel_launch(void* const* d_in, const int* in_sizes, int n_in,
                              void* d_out, int out_size, void* d_ws, size_t ws_size,
                              hipStream_t stream) {
  (void)in_sizes; (void)n_in; (void)out_size; (void)ws_size;
  const float* q  = (const float*)d_in[0];
  const float* k  = (const float*)d_in[1];
  const float* v  = (const float*)d_in[2];
  const float* W1 = (const float*)d_in[3];
  const float* b1 = (const float*)d_in[4];
  const float* W2 = (const float*)d_in[5];
  const float* b2 = (const float*)d_in[6];
  const float* W3 = (const float*)d_in[7];
  const float* b3 = (const float*)d_in[8];
  float* out = (float*)d_out;

  // workspace layout (36 MB total)
  _Float16* Qp  = (_Float16*)d_ws;                       // [h][n][e] 8 MB
  _Float16* Kp  = Qp + (size_t)BATCH * HEADS * DH;       // [h][m][e] 8 MB
  _Float16* VpT = Kp + (size_t)BATCH * HEADS * DH;       // [h][e][m] 8 MB
  float*    S   = (float*)(VpT + (size_t)BATCH * HEADS * DH);      // 8 MB
  _Float16* At  = (_Float16*)(S + (size_t)HEADS * BATCH * BATCH);  // 4 MB

  const dim3 blk(256);
  proj_kernel<<<dim3(768), blk, 0, stream>>>(q, k, v, W1, b1, W2, b2, W3, b3, Qp, Kp, VpT);
  score_kernel<<<dim3(128), blk, 0, stream>>>(Qp, Kp, S);
  softmax_kernel<<<dim3(HEADS * BATCH), dim3(64), 0, stream>>>(S, At);
  pv_kernel<<<dim3(256), blk, 0, stream>>>(At, VpT, out);
}